// Round 2
// baseline (1261.800 us; speedup 1.0000x reference)
//
#include <hip/hip_runtime.h>

// Problem constants (fixed shapes from reference)
#define NE    1024
#define CDIM  64
#define BDIM  16
#define HDIM  64
#define WDIM  64
#define NPOS  (BDIM*HDIM*WDIM)          // 65536 positions
#define ZTOT  (BDIM*CDIM*HDIM*WDIM)     // 4194304 elements

// d_out offsets (float elements), concat in reference return order
#define ZQ_OFF   0
#define LOSS_OFF 4194304
#define IDX_OFF  4194305
#define EMB_OFF  4259841
#define CS_OFF   4325377
#define EA_OFF   4326401

// workspace offsets (float elements)
#define WS_LOSS   0
#define WS_COUNTS 64
#define WS_ESUM   (64 + 1024)
#define WS_ENORM  (64 + 1024 + 65536)
#define WS_CSN    (WS_ENORM + 1024)
#define WS_ZERO_BYTES ((size_t)(64 + 1024 + 65536) * 4)

// ---------------- K0: codebook row squared norms, pre-scaled by -0.5 ----------------
// en2[j] = -0.5 * ||e_j||^2  (exact pow-2 scale; m = en2 + dot rounds identically
// to fmaf(-0.5, enorm, dot) since -0.5*x is exact)
__global__ __launch_bounds__(256) void k_enorm(const float* __restrict__ emb,
                                               float* __restrict__ en2) {
    int wid  = (blockIdx.x * blockDim.x + threadIdx.x) >> 6;   // row 0..1023
    int lane = threadIdx.x & 63;
    if (wid >= NE) return;
    float v = emb[wid * CDIM + lane];
    float s = v * v;
    #pragma unroll
    for (int off = 32; off > 0; off >>= 1) s += __shfl_xor(s, off);
    if (lane == 0) en2[wid] = -0.5f * s;
}

// ---------------- K1: argmin + z_q + loss + scatter ----------------
// Block = 256 threads = 4 waves; each wave owns one (b,h) row (64 positions, lane=w).
// Codebook is streamed through double-buffered LDS in 128-code (32KB) chunks.
// Inner loop: uniform ds_read_b128 broadcast + 4-chain fp32 fma — VALU-bound.
__global__ __launch_bounds__(256) void k_main(const float* __restrict__ z,
                                              const float* __restrict__ emb,
                                              const float* __restrict__ en2,
                                              float* __restrict__ out,
                                              float* __restrict__ counts,
                                              float* __restrict__ esum,
                                              float* __restrict__ lossacc) {
    __shared__ float ldsE[2][128 * 64];   // 2 x 32 KB
    __shared__ float ldsN[2][128];        // 2 x 512 B

    const int tid  = threadIdx.x;
    const int lane = tid & 63;                       // w
    const int bh   = blockIdx.x * 4 + (tid >> 6);    // 0..1023 = (b,h)
    const int b    = bh >> 6;
    const int h    = bh & 63;
    const int zbase = b * (CDIM * HDIM * WDIM) + h * WDIM + lane;

    // this position's 64-dim vector, coalesced across lanes, held in VGPRs
    float zr[CDIM];
    #pragma unroll
    for (int c = 0; c < CDIM; ++c) zr[c] = z[zbase + c * (HDIM * WDIM)];

    const float4* embv = (const float4*)emb;   // 2048 float4 per 128-code chunk

    float4 sreg[8];
    float  snreg = 0.f;

    // prologue: stage chunk 0
    #pragma unroll
    for (int k = 0; k < 8; ++k) sreg[k] = embv[k * 256 + tid];
    if (tid < 128) snreg = en2[tid];
    #pragma unroll
    for (int k = 0; k < 8; ++k) ((float4*)ldsE[0])[k * 256 + tid] = sreg[k];
    if (tid < 128) ldsN[0][tid] = snreg;
    __syncthreads();

    float best = -3.4e38f;
    int   bidx = 0;

    for (int ch = 0; ch < 8; ++ch) {
        const int cur = ch & 1;

        // issue next chunk's global loads into regs (land during compute)
        if (ch < 7) {
            #pragma unroll
            for (int k = 0; k < 8; ++k) sreg[k] = embv[(ch + 1) * 2048 + k * 256 + tid];
            if (tid < 128) snreg = en2[(ch + 1) * 128 + tid];
        }

        const float* Ebuf = ldsE[cur];
        const float* Nbuf = ldsN[cur];

        #pragma unroll 2
        for (int jj = 0; jj < 128; ++jj) {
            const float* e = Ebuf + jj * 64;         // wave-uniform -> broadcast
            float d0 = 0.f, d1 = 0.f, d2 = 0.f, d3 = 0.f;
            #pragma unroll
            for (int c = 0; c < 64; c += 4) {
                float4 e4 = *(const float4*)(e + c); // ds_read_b128 broadcast
                d0 = fmaf(e4.x, zr[c + 0], d0);
                d1 = fmaf(e4.y, zr[c + 1], d1);
                d2 = fmaf(e4.z, zr[c + 2], d2);
                d3 = fmaf(e4.w, zr[c + 3], d3);
            }
            float dot = (d0 + d1) + (d2 + d3);
            float m = Nbuf[jj] + dot;                // == fmaf(-0.5, enorm, dot)
            int j = ch * 128 + jj;
            if (m > best) { best = m; bidx = j; }    // strict >: first index on ties
        }
        __syncthreads();

        if (ch < 7) {
            #pragma unroll
            for (int k = 0; k < 8; ++k) ((float4*)ldsE[cur ^ 1])[k * 256 + tid] = sreg[k];
            if (tid < 128) ldsN[cur ^ 1][tid] = snreg;
            __syncthreads();
        }
    }

    // indices output (stored as float)
    out[IDX_OFF + bh * 64 + lane] = (float)bidx;

    // fetch selected codebook row (per-lane divergent gather, L2-resident)
    const float4* ev = (const float4*)(emb + bidx * CDIM);
    float lsum = 0.f;

    #define PROC(ZQ, CC)                                                    \
        do {                                                                \
            const int c_ = (CC);                                            \
            float zv_ = zr[c_];                                             \
            float df_ = (ZQ) - zv_;                                         \
            out[ZQ_OFF + zbase + c_ * (HDIM * WDIM)] = zv_ + df_;           \
            lsum = fmaf(df_, df_, lsum);                                    \
            atomicAdd(&esum[bidx * CDIM + c_], zv_);                        \
        } while (0)

    #pragma unroll
    for (int k = 0; k < 16; ++k) {
        float4 e4 = ev[k];
        PROC(e4.x, 4 * k + 0);
        PROC(e4.y, 4 * k + 1);
        PROC(e4.z, 4 * k + 2);
        PROC(e4.w, 4 * k + 3);
    }
    #undef PROC

    atomicAdd(&counts[bidx], 1.0f);

    // wave-reduce commitment-loss partial, one atomic per wave
    #pragma unroll
    for (int off = 32; off > 0; off >>= 1) lsum += __shfl_xor(lsum, off);
    if (lane == 0) atomicAdd(lossacc, lsum);
}

// ---------------- K2: cluster-size EMA + n-sum + loss ----------------
__global__ __launch_bounds__(1024) void k_cluster(const float* __restrict__ cs_in,
                                                  const float* __restrict__ counts,
                                                  const float* __restrict__ lossacc,
                                                  float* __restrict__ out,
                                                  float* __restrict__ csn) {
    __shared__ float red[NE];
    int j = threadIdx.x;
    float ncs = 0.99f * cs_in[j] + 0.01f * counts[j];
    out[CS_OFF + j] = ncs;
    red[j] = ncs;
    __syncthreads();
    #pragma unroll
    for (int s = 512; s > 0; s >>= 1) {
        if (j < s) red[j] += red[j + s];
        __syncthreads();
    }
    float n = red[0];
    float cs = ((ncs + 1e-5f) / (n + 0.01024f)) * n;   // (ncs+eps)/(n+NE*eps)*n
    csn[j] = cs;
    if (j == 0) out[LOSS_OFF] = 0.25f * (lossacc[0] * (1.0f / (float)ZTOT));
}

// ---------------- K3: embed_avg EMA + normalized embedding ----------------
__global__ __launch_bounds__(256) void k_embed(const float* __restrict__ ea_in,
                                               const float* __restrict__ esum,
                                               const float* __restrict__ csn,
                                               float* __restrict__ out) {
    int i = blockIdx.x * 256 + threadIdx.x;   // 0..65535
    float nea = 0.99f * ea_in[i] + 0.01f * esum[i];
    out[EA_OFF + i] = nea;
    out[EMB_OFF + i] = nea / csn[i >> 6];
}

extern "C" void kernel_launch(void* const* d_in, const int* in_sizes, int n_in,
                              void* d_out, int out_size, void* d_ws, size_t ws_size,
                              hipStream_t stream) {
    const float* z   = (const float*)d_in[0];
    const float* emb = (const float*)d_in[1];
    const float* cs  = (const float*)d_in[2];
    const float* ea  = (const float*)d_in[3];
    float* out = (float*)d_out;
    float* ws  = (float*)d_ws;

    hipMemsetAsync(d_ws, 0, WS_ZERO_BYTES, stream);                 // loss + counts + esum
    k_enorm<<<256, 256, 0, stream>>>(emb, ws + WS_ENORM);
    k_main<<<256, 256, 0, stream>>>(z, emb, ws + WS_ENORM, out,
                                    ws + WS_COUNTS, ws + WS_ESUM, ws + WS_LOSS);
    k_cluster<<<1, 1024, 0, stream>>>(cs, ws + WS_COUNTS, ws + WS_LOSS, out, ws + WS_CSN);
    k_embed<<<256, 256, 0, stream>>>(ea, ws + WS_ESUM, ws + WS_CSN, out);
}

// Round 3
// 1021.356 us; speedup vs baseline: 1.2354x; 1.2354x over previous
//
#include <hip/hip_runtime.h>

// Problem constants (fixed shapes from reference)
#define NE    1024
#define CDIM  64
#define BDIM  16
#define HDIM  64
#define WDIM  64
#define NPOS  (BDIM*HDIM*WDIM)          // 65536 positions
#define ZTOT  (BDIM*CDIM*HDIM*WDIM)     // 4194304 elements

// d_out offsets (float elements), concat in reference return order
#define ZQ_OFF   0
#define LOSS_OFF 4194304
#define IDX_OFF  4194305
#define EMB_OFF  4259841
#define CS_OFF   4325377
#define EA_OFF   4326401

// workspace offsets (float elements)
#define WS_LOSS   0
#define WS_COUNTS 64
#define WS_ESUM   (64 + 1024)                  // 1088
#define WS_KEYS   (WS_ESUM + 65536)            // 66624 (8B-aligned: 66624*4 % 8 == 0)
#define WS_ENORM  (WS_KEYS + 131072)           // 197696
#define WS_CSN    (WS_ENORM + 1024)
#define WS_ZERO_BYTES ((size_t)(WS_KEYS + 131072) * 4)   // loss+counts+esum+keys

// monotone float->uint mapping: a<b  <=>  ordf(a)<ordf(b)
__device__ __forceinline__ unsigned ordf(float x) {
    unsigned b = __float_as_uint(x);
    return (b & 0x80000000u) ? ~b : (b | 0x80000000u);
}

// ---------------- K0: codebook row norms, pre-scaled by -0.5 ----------------
__global__ __launch_bounds__(256) void k_enorm(const float* __restrict__ emb,
                                               float* __restrict__ en2) {
    int wid  = (blockIdx.x * blockDim.x + threadIdx.x) >> 6;   // row 0..1023
    int lane = threadIdx.x & 63;
    if (wid >= NE) return;
    float v = emb[wid * CDIM + lane];
    float s = v * v;
    #pragma unroll
    for (int off = 32; off > 0; off >>= 1) s += __shfl_xor(s, off);
    if (lane == 0) en2[wid] = -0.5f * s;
}

// ---------------- K1: argmin over a 128-code chunk ----------------
// Grid: 2048 blocks = 256 row-groups x 8 code-chunks. Block = 4 waves;
// wave i owns row bh = rg*4+i (64 positions, lane=w), scans codes
// [ch*128, ch*128+128) staged once in 32KB LDS. Partial argmin merged via
// u64 atomicMax key = (ord(m)<<32)|(1023-j)  -> max m, tie -> min j,
// identical to a linear first-argmin scan.
__global__ __launch_bounds__(256, 4) void k_argmin(const float* __restrict__ z,
                                                   const float* __restrict__ emb,
                                                   const float* __restrict__ en2,
                                                   unsigned long long* __restrict__ keys) {
    __shared__ float E[128 * 64];   // 32 KB
    __shared__ float Nn[128];

    const int tid  = threadIdx.x;
    const int lane = tid & 63;                        // w
    const int rg   = blockIdx.x >> 3;                 // row group 0..255
    const int ch   = blockIdx.x & 7;                  // code chunk 0..7
    const int bh   = rg * 4 + (tid >> 6);             // 0..1023
    const int b    = bh >> 6;
    const int h    = bh & 63;
    const int zbase = b * (CDIM * HDIM * WDIM) + h * WDIM + lane;

    // cooperative stage: 32KB chunk (2048 float4 / 256 threads = 8 each)
    const float4* src = (const float4*)(emb + ch * 128 * CDIM);
    #pragma unroll
    for (int k = 0; k < 8; ++k) ((float4*)E)[k * 256 + tid] = src[k * 256 + tid];
    if (tid < 128) Nn[tid] = en2[ch * 128 + tid];

    // this position's 64-dim vector (coalesced across lanes)
    float zr[CDIM];
    #pragma unroll
    for (int c = 0; c < CDIM; ++c) zr[c] = z[zbase + c * (HDIM * WDIM)];

    __syncthreads();

    float best = -3.4e38f;
    int   bidx = ch * 128;

    #pragma unroll 2
    for (int jj = 0; jj < 128; ++jj) {
        const float* e = E + jj * 64;                 // wave-uniform -> broadcast
        float d0 = 0.f, d1 = 0.f, d2 = 0.f, d3 = 0.f;
        #pragma unroll
        for (int c = 0; c < 64; c += 4) {
            float4 e4 = *(const float4*)(e + c);      // ds_read_b128
            d0 = fmaf(e4.x, zr[c + 0], d0);
            d1 = fmaf(e4.y, zr[c + 1], d1);
            d2 = fmaf(e4.z, zr[c + 2], d2);
            d3 = fmaf(e4.w, zr[c + 3], d3);
        }
        float dot = (d0 + d1) + (d2 + d3);
        float m = Nn[jj] + dot;                       // == fmaf(-0.5, norm, dot)
        int j = ch * 128 + jj;
        if (m > best) { best = m; bidx = j; }         // strict >: first index wins
    }

    unsigned long long key =
        ((unsigned long long)ordf(best) << 32) | (unsigned)(1023 - bidx);
    atomicMax(&keys[bh * 64 + lane], key);
}

// ---------------- K1b: finish — indices, z_q, loss, scatter ----------------
__global__ __launch_bounds__(256) void k_finish(const float* __restrict__ z,
                                                const float* __restrict__ emb,
                                                const unsigned long long* __restrict__ keys,
                                                float* __restrict__ out,
                                                float* __restrict__ counts,
                                                float* __restrict__ esum,
                                                float* __restrict__ lossacc) {
    const int tid  = threadIdx.x;
    const int lane = tid & 63;
    const int bh   = blockIdx.x * 4 + (tid >> 6);     // 0..1023
    const int b    = bh >> 6;
    const int h    = bh & 63;
    const int zbase = b * (CDIM * HDIM * WDIM) + h * WDIM + lane;

    const unsigned long long key = keys[bh * 64 + lane];
    const int bidx = 1023 - (int)(unsigned)(key & 0xFFFFFFFFull);

    out[IDX_OFF + bh * 64 + lane] = (float)bidx;

    float zr[CDIM];
    #pragma unroll
    for (int c = 0; c < CDIM; ++c) zr[c] = z[zbase + c * (HDIM * WDIM)];

    const float4* ev = (const float4*)(emb + bidx * CDIM);
    float lsum = 0.f;

    #define PROC(ZQ, CC)                                                    \
        do {                                                                \
            const int c_ = (CC);                                            \
            float zv_ = zr[c_];                                             \
            float df_ = (ZQ) - zv_;                                         \
            out[ZQ_OFF + zbase + c_ * (HDIM * WDIM)] = zv_ + df_;           \
            lsum = fmaf(df_, df_, lsum);                                    \
            atomicAdd(&esum[bidx * CDIM + c_], zv_);                        \
        } while (0)

    #pragma unroll
    for (int k = 0; k < 16; ++k) {
        float4 e4 = ev[k];
        PROC(e4.x, 4 * k + 0);
        PROC(e4.y, 4 * k + 1);
        PROC(e4.z, 4 * k + 2);
        PROC(e4.w, 4 * k + 3);
    }
    #undef PROC

    atomicAdd(&counts[bidx], 1.0f);

    #pragma unroll
    for (int off = 32; off > 0; off >>= 1) lsum += __shfl_xor(lsum, off);
    if (lane == 0) atomicAdd(lossacc, lsum);
}

// ---------------- K2: cluster-size EMA + n-sum + loss ----------------
__global__ __launch_bounds__(1024) void k_cluster(const float* __restrict__ cs_in,
                                                  const float* __restrict__ counts,
                                                  const float* __restrict__ lossacc,
                                                  float* __restrict__ out,
                                                  float* __restrict__ csn) {
    __shared__ float red[NE];
    int j = threadIdx.x;
    float ncs = 0.99f * cs_in[j] + 0.01f * counts[j];
    out[CS_OFF + j] = ncs;
    red[j] = ncs;
    __syncthreads();
    #pragma unroll
    for (int s = 512; s > 0; s >>= 1) {
        if (j < s) red[j] += red[j + s];
        __syncthreads();
    }
    float n = red[0];
    float cs = ((ncs + 1e-5f) / (n + 0.01024f)) * n;   // (ncs+eps)/(n+NE*eps)*n
    csn[j] = cs;
    if (j == 0) out[LOSS_OFF] = 0.25f * (lossacc[0] * (1.0f / (float)ZTOT));
}

// ---------------- K3: embed_avg EMA + normalized embedding ----------------
__global__ __launch_bounds__(256) void k_embed(const float* __restrict__ ea_in,
                                               const float* __restrict__ esum,
                                               const float* __restrict__ csn,
                                               float* __restrict__ out) {
    int i = blockIdx.x * 256 + threadIdx.x;   // 0..65535
    float nea = 0.99f * ea_in[i] + 0.01f * esum[i];
    out[EA_OFF + i] = nea;
    out[EMB_OFF + i] = nea / csn[i >> 6];
}

extern "C" void kernel_launch(void* const* d_in, const int* in_sizes, int n_in,
                              void* d_out, int out_size, void* d_ws, size_t ws_size,
                              hipStream_t stream) {
    const float* z   = (const float*)d_in[0];
    const float* emb = (const float*)d_in[1];
    const float* cs  = (const float*)d_in[2];
    const float* ea  = (const float*)d_in[3];
    float* out = (float*)d_out;
    float* ws  = (float*)d_ws;

    hipMemsetAsync(d_ws, 0, WS_ZERO_BYTES, stream);   // loss + counts + esum + keys
    k_enorm<<<256, 256, 0, stream>>>(emb, ws + WS_ENORM);
    k_argmin<<<2048, 256, 0, stream>>>(z, emb, ws + WS_ENORM,
                                       (unsigned long long*)(ws + WS_KEYS));
    k_finish<<<256, 256, 0, stream>>>(z, emb,
                                      (const unsigned long long*)(ws + WS_KEYS),
                                      out, ws + WS_COUNTS, ws + WS_ESUM, ws + WS_LOSS);
    k_cluster<<<1, 1024, 0, stream>>>(cs, ws + WS_COUNTS, ws + WS_LOSS, out, ws + WS_CSN);
    k_embed<<<256, 256, 0, stream>>>(ea, ws + WS_ESUM, ws + WS_CSN, out);
}

// Round 4
// 781.442 us; speedup vs baseline: 1.6147x; 1.3070x over previous
//
#include <hip/hip_runtime.h>

// Problem constants (fixed shapes from reference)
#define NE    1024
#define CDIM  64
#define BDIM  16
#define HDIM  64
#define WDIM  64
#define NPOS  (BDIM*HDIM*WDIM)          // 65536 positions
#define ZTOT  (BDIM*CDIM*HDIM*WDIM)     // 4194304 elements

// d_out offsets (float elements), concat in reference return order
#define ZQ_OFF   0
#define LOSS_OFF 4194304
#define IDX_OFF  4194305
#define EMB_OFF  4259841
#define CS_OFF   4325377
#define EA_OFF   4326401

// workspace offsets (float elements)
#define WS_LOSS   0
#define WS_COUNTS 64
#define WS_ESUM   (64 + 1024)                  // 1088
#define WS_ENORM  (WS_ESUM + 65536)            // 66624
#define WS_CSN    (WS_ENORM + 1024)
#define WS_ZERO_BYTES ((size_t)(64 + 1024 + 65536) * 4)   // loss+counts+esum

// monotone float->uint mapping: a<b  <=>  ordf(a)<ordf(b)
__device__ __forceinline__ unsigned ordf(float x) {
    unsigned b = __float_as_uint(x);
    return (b & 0x80000000u) ? ~b : (b | 0x80000000u);
}

// ---------------- K0: codebook row norms, pre-scaled by -0.5 ----------------
__global__ __launch_bounds__(256) void k_enorm(const float* __restrict__ emb,
                                               float* __restrict__ en2) {
    int wid  = (blockIdx.x * blockDim.x + threadIdx.x) >> 6;   // row 0..1023
    int lane = threadIdx.x & 63;
    if (wid >= NE) return;
    float v = emb[wid * CDIM + lane];
    float s = v * v;
    #pragma unroll
    for (int off = 32; off > 0; off >>= 1) s += __shfl_xor(s, off);
    if (lane == 0) en2[wid] = -0.5f * s;
}

// ---------------- K1: fused argmin GEMM + emit ----------------
// Grid: 512 blocks (2 bh-rows = 128 positions each) x 256 threads (4 waves).
// Register-blocked fp32 GEMM: wave tile 64 pos x 64 codes, lane tile 8x8.
// LDS c-major tiles: zs[c][128 pos], Et[c][128 codes] -> conflict-free b128
// reads (8 distinct 16B units across lane groups). Codebook streamed in 8
// chunks of 128 codes. Argmin via max(dot-0.5||e||^2), key=(ord<<32)|(1023-j)
// => max-m-then-min-j == reference first-argmin. Emit phase reuses LDS z.
__global__ __launch_bounds__(256) void k_fused(const float* __restrict__ z,
                                               const float* __restrict__ emb,
                                               const float* __restrict__ en2,
                                               float* __restrict__ out,
                                               float* __restrict__ counts,
                                               float* __restrict__ esum,
                                               float* __restrict__ lossacc) {
    __shared__ float zs[64 * 128];            // 32 KB  [c][pl]
    __shared__ float Et[64 * 128];            // 32 KB  [c][jl]
    __shared__ float Nn[128];                 // -0.5||e||^2 for chunk
    __shared__ unsigned long long keyL[128];  // per-position argmin key

    const int t    = threadIdx.x;
    const int lane = t & 63;
    const int wid  = t >> 6;          // wave 0..3
    const int wr   = wid >> 1;        // position half (0..1)
    const int wc   = wid & 1;         // code half (0..1)
    const int lr   = lane >> 3;       // 0..7  position octet selector
    const int lc   = lane & 7;        // 0..7  code octet selector
    const int zb   = wr * 64 + lr * 8;   // lane's first pl
    const int eb   = wc * 64 + lc * 8;   // lane's first jl

    const int blk = blockIdx.x;       // 0..511

    if (t < 128) keyL[t] = 0ull;

    // ---- stage z tile: 2 bh-rows, c-major zs[c][r*64+w] ----
    {
        const int w4 = t & 15;            // float4 index over w
        const int cg = t >> 4;            // 16 c's per pass
        #pragma unroll
        for (int r = 0; r < 2; ++r) {
            const int bh = blk * 2 + r;
            const int b = bh >> 6, h = bh & 63;
            const float* zrow = z + (size_t)b * (CDIM * HDIM * WDIM) + h * WDIM;
            #pragma unroll
            for (int pass = 0; pass < 4; ++pass) {
                const int c = pass * 16 + cg;
                float4 v = *(const float4*)(zrow + c * (HDIM * WDIM) + w4 * 4);
                *(float4*)&zs[c * 128 + r * 64 + w4 * 4] = v;
            }
        }
    }

    const float4* embv = (const float4*)emb;

    float best[8];
    int   bidx[8];
    #pragma unroll
    for (int pi = 0; pi < 8; ++pi) { best[pi] = -3.4e38f; bidx[pi] = 0; }

    for (int ch = 0; ch < 8; ++ch) {
        __syncthreads();   // protect Et/Nn reuse

        // ---- stage E chunk transposed: Et[c][jl] (uncoalesced L2 reads) ----
        {
            const int jl = t & 127;
            const int q  = t >> 7;        // 0..1
            #pragma unroll
            for (int qq = 0; qq < 8; ++qq) {
                const int quad = q * 8 + qq;
                float4 e4 = embv[(ch * 128 + jl) * 16 + quad];
                Et[(quad * 4 + 0) * 128 + jl] = e4.x;
                Et[(quad * 4 + 1) * 128 + jl] = e4.y;
                Et[(quad * 4 + 2) * 128 + jl] = e4.z;
                Et[(quad * 4 + 3) * 128 + jl] = e4.w;
            }
        }
        if (t < 128) Nn[t] = en2[ch * 128 + t];
        __syncthreads();

        // ---- GEMM micro-tile: acc[8 pos][8 codes] over 64 channels ----
        float acc[8][8];
        #pragma unroll
        for (int pi = 0; pi < 8; ++pi)
            #pragma unroll
            for (int jj = 0; jj < 8; ++jj) acc[pi][jj] = 0.f;

        #pragma unroll 4
        for (int c = 0; c < 64; ++c) {
            float4 za = *(const float4*)&zs[c * 128 + zb];
            float4 zb4 = *(const float4*)&zs[c * 128 + zb + 4];
            float4 ea = *(const float4*)&Et[c * 128 + eb];
            float4 eb4 = *(const float4*)&Et[c * 128 + eb + 4];
            float zv[8] = {za.x, za.y, za.z, za.w, zb4.x, zb4.y, zb4.z, zb4.w};
            float ev[8] = {ea.x, ea.y, ea.z, ea.w, eb4.x, eb4.y, eb4.z, eb4.w};
            #pragma unroll
            for (int pi = 0; pi < 8; ++pi)
                #pragma unroll
                for (int jj = 0; jj < 8; ++jj)
                    acc[pi][jj] = fmaf(zv[pi], ev[jj], acc[pi][jj]);
        }

        // ---- fold argmin for this chunk ----
        float n2[8];
        {
            float4 na = *(const float4*)&Nn[eb];
            float4 nb = *(const float4*)&Nn[eb + 4];
            n2[0]=na.x; n2[1]=na.y; n2[2]=na.z; n2[3]=na.w;
            n2[4]=nb.x; n2[5]=nb.y; n2[6]=nb.z; n2[7]=nb.w;
        }
        const int jbase = ch * 128 + eb;
        #pragma unroll
        for (int pi = 0; pi < 8; ++pi) {
            #pragma unroll
            for (int jj = 0; jj < 8; ++jj) {
                float m = acc[pi][jj] + n2[jj];
                if (m > best[pi]) { best[pi] = m; bidx[pi] = jbase + jj; }
            }
        }
    }

    // ---- merge across the 8 lc-lanes sharing the same positions ----
    unsigned long long key[8];
    #pragma unroll
    for (int pi = 0; pi < 8; ++pi)
        key[pi] = ((unsigned long long)ordf(best[pi]) << 32) |
                  (unsigned)(1023 - bidx[pi]);
    #pragma unroll
    for (int off = 1; off < 8; off <<= 1) {
        #pragma unroll
        for (int pi = 0; pi < 8; ++pi) {
            unsigned long long o = __shfl_xor(key[pi], off);
            key[pi] = (o > key[pi]) ? o : key[pi];
        }
    }
    #pragma unroll
    for (int pi = 0; pi < 8; ++pi)
        if (lc == pi) atomicMax(&keyL[zb + pi], key[pi]);

    __syncthreads();

    // ---- emit: idx, z_q (straight-through), loss, counts, esum ----
    {
        const int w = t & 63;
        const int g = t >> 6;
        const int r = g & 1;
        const int chalf = g >> 1;
        const int pl = r * 64 + w;
        const int bx = 1023 - (int)(unsigned)(keyL[pl] & 0xFFFFFFFFull);

        if (chalf == 0) {
            out[IDX_OFF + blk * 128 + pl] = (float)bx;
            atomicAdd(&counts[bx], 1.0f);
        }

        const int bh = blk * 2 + r;
        const int b = bh >> 6, h = bh & 63;
        float* zqrow = out + ZQ_OFF + (size_t)b * (CDIM * HDIM * WDIM) + h * WDIM + w;

        float lsum = 0.f;
        #pragma unroll
        for (int q = 0; q < 8; ++q) {
            float4 e4 = embv[bx * 16 + chalf * 8 + q];
            #pragma unroll
            for (int k = 0; k < 4; ++k) {
                const int c = chalf * 32 + q * 4 + k;
                float zv = zs[c * 128 + pl];
                float ev = (k == 0) ? e4.x : (k == 1) ? e4.y : (k == 2) ? e4.z : e4.w;
                float df = ev - zv;
                zqrow[c * (HDIM * WDIM)] = zv + df;   // z + (z_q - z)
                lsum = fmaf(df, df, lsum);
                atomicAdd(&esum[bx * CDIM + c], zv);
            }
        }

        #pragma unroll
        for (int off = 32; off > 0; off >>= 1) lsum += __shfl_xor(lsum, off);
        if (w == 0) atomicAdd(lossacc, lsum);
    }
}

// ---------------- K2: cluster-size EMA + n-sum + loss ----------------
__global__ __launch_bounds__(1024) void k_cluster(const float* __restrict__ cs_in,
                                                  const float* __restrict__ counts,
                                                  const float* __restrict__ lossacc,
                                                  float* __restrict__ out,
                                                  float* __restrict__ csn) {
    __shared__ float red[NE];
    int j = threadIdx.x;
    float ncs = 0.99f * cs_in[j] + 0.01f * counts[j];
    out[CS_OFF + j] = ncs;
    red[j] = ncs;
    __syncthreads();
    #pragma unroll
    for (int s = 512; s > 0; s >>= 1) {
        if (j < s) red[j] += red[j + s];
        __syncthreads();
    }
    float n = red[0];
    float cs = ((ncs + 1e-5f) / (n + 0.01024f)) * n;   // (ncs+eps)/(n+NE*eps)*n
    csn[j] = cs;
    if (j == 0) out[LOSS_OFF] = 0.25f * (lossacc[0] * (1.0f / (float)ZTOT));
}

// ---------------- K3: embed_avg EMA + normalized embedding ----------------
__global__ __launch_bounds__(256) void k_embed(const float* __restrict__ ea_in,
                                               const float* __restrict__ esum,
                                               const float* __restrict__ csn,
                                               float* __restrict__ out) {
    int i = blockIdx.x * 256 + threadIdx.x;   // 0..65535
    float nea = 0.99f * ea_in[i] + 0.01f * esum[i];
    out[EA_OFF + i] = nea;
    out[EMB_OFF + i] = nea / csn[i >> 6];
}

extern "C" void kernel_launch(void* const* d_in, const int* in_sizes, int n_in,
                              void* d_out, int out_size, void* d_ws, size_t ws_size,
                              hipStream_t stream) {
    const float* z   = (const float*)d_in[0];
    const float* emb = (const float*)d_in[1];
    const float* cs  = (const float*)d_in[2];
    const float* ea  = (const float*)d_in[3];
    float* out = (float*)d_out;
    float* ws  = (float*)d_ws;

    hipMemsetAsync(d_ws, 0, WS_ZERO_BYTES, stream);   // loss + counts + esum
    k_enorm<<<256, 256, 0, stream>>>(emb, ws + WS_ENORM);
    k_fused<<<512, 256, 0, stream>>>(z, emb, ws + WS_ENORM, out,
                                     ws + WS_COUNTS, ws + WS_ESUM, ws + WS_LOSS);
    k_cluster<<<1, 1024, 0, stream>>>(cs, ws + WS_COUNTS, ws + WS_LOSS, out, ws + WS_CSN);
    k_embed<<<256, 256, 0, stream>>>(ea, ws + WS_ESUM, ws + WS_CSN, out);
}

// Round 5
// 298.171 us; speedup vs baseline: 4.2318x; 2.6208x over previous
//
#include <hip/hip_runtime.h>

// Problem constants (fixed shapes from reference)
#define NE    1024
#define CDIM  64
#define BDIM  16
#define HDIM  64
#define WDIM  64
#define NPOS  (BDIM*HDIM*WDIM)          // 65536 positions
#define ZTOT  (BDIM*CDIM*HDIM*WDIM)     // 4194304 elements

// d_out offsets (float elements), concat in reference return order
#define ZQ_OFF   0
#define LOSS_OFF 4194304
#define IDX_OFF  4194305
#define EMB_OFF  4259841
#define CS_OFF   4325377
#define EA_OFF   4326401

// workspace offsets (float elements)
#define WS_LOSS   0
#define WS_COUNTS 64
#define WS_ESUM   (64 + 1024)                  // 1088
#define WS_ENORM  (WS_ESUM + 65536)            // 66624
#define WS_CSN    (WS_ENORM + 1024)

// monotone float->uint mapping: a<b  <=>  ordf(a)<ordf(b)
__device__ __forceinline__ unsigned ordf(float x) {
    unsigned b = __float_as_uint(x);
    return (b & 0x80000000u) ? ~b : (b | 0x80000000u);
}

// ---------------- K0: codebook row norms, pre-scaled by -0.5 ----------------
__global__ __launch_bounds__(256) void k_enorm(const float* __restrict__ emb,
                                               float* __restrict__ en2) {
    int wid  = (blockIdx.x * blockDim.x + threadIdx.x) >> 6;   // row 0..1023
    int lane = threadIdx.x & 63;
    if (wid >= NE) return;
    float v = emb[wid * CDIM + lane];
    float s = v * v;
    #pragma unroll
    for (int off = 32; off > 0; off >>= 1) s += __shfl_xor(s, off);
    if (lane == 0) en2[wid] = -0.5f * s;
}

// ---------------- K1: fused argmin GEMM + z_q/idx/loss emit ----------------
// Grid: 512 blocks (2 bh-rows = 128 positions each) x 256 threads (4 waves).
// Register-blocked fp32 GEMM: wave tile 64 pos x 64 codes, lane tile 8x8.
// NO global atomics here (they were the 200 GB/s wall): esum/counts moved
// to k_scatter. Argmin key=(ord(m)<<32)|(1023-j) => max-m-then-min-j ==
// reference first-argmin.
__global__ __launch_bounds__(256) void k_fused(const float* __restrict__ z,
                                               const float* __restrict__ emb,
                                               const float* __restrict__ en2,
                                               float* __restrict__ out,
                                               float* __restrict__ lossacc) {
    __shared__ float zs[64 * 128];            // 32 KB  [c][pl]
    __shared__ float Et[64 * 128];            // 32 KB  [c][jl]
    __shared__ float Nn[128];                 // -0.5||e||^2 for chunk
    __shared__ unsigned long long keyL[128];  // per-position argmin key

    const int t    = threadIdx.x;
    const int lane = t & 63;
    const int wid  = t >> 6;          // wave 0..3
    const int wr   = wid >> 1;        // position half (0..1)
    const int wc   = wid & 1;         // code half (0..1)
    const int lr   = lane >> 3;       // 0..7  position octet selector
    const int lc   = lane & 7;        // 0..7  code octet selector
    const int zb   = wr * 64 + lr * 8;   // lane's first pl
    const int eb   = wc * 64 + lc * 8;   // lane's first jl

    const int blk = blockIdx.x;       // 0..511

    if (t < 128) keyL[t] = 0ull;

    // ---- stage z tile: 2 bh-rows, c-major zs[c][r*64+w] ----
    {
        const int w4 = t & 15;            // float4 index over w
        const int cg = t >> 4;            // 16 c's per pass
        #pragma unroll
        for (int r = 0; r < 2; ++r) {
            const int bh = blk * 2 + r;
            const int b = bh >> 6, h = bh & 63;
            const float* zrow = z + (size_t)b * (CDIM * HDIM * WDIM) + h * WDIM;
            #pragma unroll
            for (int pass = 0; pass < 4; ++pass) {
                const int c = pass * 16 + cg;
                float4 v = *(const float4*)(zrow + c * (HDIM * WDIM) + w4 * 4);
                *(float4*)&zs[c * 128 + r * 64 + w4 * 4] = v;
            }
        }
    }

    const float4* embv = (const float4*)emb;

    float best[8];
    int   bidx[8];
    #pragma unroll
    for (int pi = 0; pi < 8; ++pi) { best[pi] = -3.4e38f; bidx[pi] = 0; }

    for (int ch = 0; ch < 8; ++ch) {
        __syncthreads();   // protect Et/Nn reuse

        // ---- stage E chunk transposed: Et[c][jl] ----
        {
            const int jl = t & 127;
            const int q  = t >> 7;        // 0..1
            #pragma unroll
            for (int qq = 0; qq < 8; ++qq) {
                const int quad = q * 8 + qq;
                float4 e4 = embv[(ch * 128 + jl) * 16 + quad];
                Et[(quad * 4 + 0) * 128 + jl] = e4.x;
                Et[(quad * 4 + 1) * 128 + jl] = e4.y;
                Et[(quad * 4 + 2) * 128 + jl] = e4.z;
                Et[(quad * 4 + 3) * 128 + jl] = e4.w;
            }
        }
        if (t < 128) Nn[t] = en2[ch * 128 + t];
        __syncthreads();

        // ---- GEMM micro-tile: acc[8 pos][8 codes] over 64 channels ----
        float acc[8][8];
        #pragma unroll
        for (int pi = 0; pi < 8; ++pi)
            #pragma unroll
            for (int jj = 0; jj < 8; ++jj) acc[pi][jj] = 0.f;

        #pragma unroll 4
        for (int c = 0; c < 64; ++c) {
            float4 za = *(const float4*)&zs[c * 128 + zb];
            float4 zb4 = *(const float4*)&zs[c * 128 + zb + 4];
            float4 ea = *(const float4*)&Et[c * 128 + eb];
            float4 eb4 = *(const float4*)&Et[c * 128 + eb + 4];
            float zv[8] = {za.x, za.y, za.z, za.w, zb4.x, zb4.y, zb4.z, zb4.w};
            float ev[8] = {ea.x, ea.y, ea.z, ea.w, eb4.x, eb4.y, eb4.z, eb4.w};
            #pragma unroll
            for (int pi = 0; pi < 8; ++pi)
                #pragma unroll
                for (int jj = 0; jj < 8; ++jj)
                    acc[pi][jj] = fmaf(zv[pi], ev[jj], acc[pi][jj]);
        }

        // ---- fold argmin for this chunk ----
        float n2[8];
        {
            float4 na = *(const float4*)&Nn[eb];
            float4 nb = *(const float4*)&Nn[eb + 4];
            n2[0]=na.x; n2[1]=na.y; n2[2]=na.z; n2[3]=na.w;
            n2[4]=nb.x; n2[5]=nb.y; n2[6]=nb.z; n2[7]=nb.w;
        }
        const int jbase = ch * 128 + eb;
        #pragma unroll
        for (int pi = 0; pi < 8; ++pi) {
            #pragma unroll
            for (int jj = 0; jj < 8; ++jj) {
                float m = acc[pi][jj] + n2[jj];
                if (m > best[pi]) { best[pi] = m; bidx[pi] = jbase + jj; }
            }
        }
    }

    // ---- merge across the 8 lc-lanes sharing the same positions ----
    unsigned long long key[8];
    #pragma unroll
    for (int pi = 0; pi < 8; ++pi)
        key[pi] = ((unsigned long long)ordf(best[pi]) << 32) |
                  (unsigned)(1023 - bidx[pi]);
    #pragma unroll
    for (int off = 1; off < 8; off <<= 1) {
        #pragma unroll
        for (int pi = 0; pi < 8; ++pi) {
            unsigned long long o = __shfl_xor(key[pi], off);
            key[pi] = (o > key[pi]) ? o : key[pi];
        }
    }
    #pragma unroll
    for (int pi = 0; pi < 8; ++pi)
        if (lc == pi) atomicMax(&keyL[zb + pi], key[pi]);

    __syncthreads();

    // ---- emit: idx, z_q (straight-through), loss ----
    {
        const int w = t & 63;
        const int g = t >> 6;
        const int r = g & 1;
        const int chalf = g >> 1;
        const int pl = r * 64 + w;
        const int bx = 1023 - (int)(unsigned)(keyL[pl] & 0xFFFFFFFFull);

        if (chalf == 0) out[IDX_OFF + blk * 128 + pl] = (float)bx;

        const int bh = blk * 2 + r;
        const int b = bh >> 6, h = bh & 63;
        float* zqrow = out + ZQ_OFF + (size_t)b * (CDIM * HDIM * WDIM) + h * WDIM + w;

        float lsum = 0.f;
        #pragma unroll
        for (int q = 0; q < 8; ++q) {
            float4 e4 = embv[bx * 16 + chalf * 8 + q];
            #pragma unroll
            for (int k = 0; k < 4; ++k) {
                const int c = chalf * 32 + q * 4 + k;
                float zv = zs[c * 128 + pl];
                float ev = (k == 0) ? e4.x : (k == 1) ? e4.y : (k == 2) ? e4.z : e4.w;
                float df = ev - zv;
                zqrow[c * (HDIM * WDIM)] = zv + df;   // z + (z_q - z)
                lsum = fmaf(df, df, lsum);
            }
        }

        #pragma unroll
        for (int off = 32; off > 0; off >>= 1) lsum += __shfl_xor(lsum, off);
        if (w == 0) atomicAdd(lossacc, lsum);
    }
}

// ---------------- K1b: esum/counts via per-channel LDS privatization ----------------
// 64 blocks (one per channel c) x 1024 threads. Block streams all 65536
// (idx, z[.,c]) pairs coalesced, accumulates esum[.][c] in LDS (ds_add_f32),
// then plain-stores its column. Block c==0 also produces counts (exact
// integer fp32 adds -> bitwise-identical cluster_size path). NO global atomics.
__global__ __launch_bounds__(1024) void k_scatter(const float* __restrict__ z,
                                                  const float* __restrict__ out_idx,
                                                  float* __restrict__ esum,
                                                  float* __restrict__ counts) {
    __shared__ float accJ[NE];
    __shared__ float cntJ[NE];

    const int t = threadIdx.x;
    const int c = blockIdx.x;          // 0..63
    accJ[t] = 0.f;
    cntJ[t] = 0.f;
    __syncthreads();

    const bool do_cnt = (c == 0);
    #pragma unroll 4
    for (int p = t; p < NPOS; p += 1024) {
        const int j = (int)out_idx[p];                 // exact for 0..1023
        const int b = p >> 12, hw = p & 4095;
        const float zv = z[(size_t)b * (CDIM * HDIM * WDIM) + c * (HDIM * WDIM) + hw];
        atomicAdd(&accJ[j], zv);                       // ds_add_f32
        if (do_cnt) atomicAdd(&cntJ[j], 1.0f);
    }
    __syncthreads();

    esum[t * CDIM + c] = accJ[t];
    if (do_cnt) counts[t] = cntJ[t];
}

// ---------------- K2: cluster-size EMA + n-sum + loss ----------------
__global__ __launch_bounds__(1024) void k_cluster(const float* __restrict__ cs_in,
                                                  const float* __restrict__ counts,
                                                  const float* __restrict__ lossacc,
                                                  float* __restrict__ out,
                                                  float* __restrict__ csn) {
    __shared__ float red[NE];
    int j = threadIdx.x;
    float ncs = 0.99f * cs_in[j] + 0.01f * counts[j];
    out[CS_OFF + j] = ncs;
    red[j] = ncs;
    __syncthreads();
    #pragma unroll
    for (int s = 512; s > 0; s >>= 1) {
        if (j < s) red[j] += red[j + s];
        __syncthreads();
    }
    float n = red[0];
    float cs = ((ncs + 1e-5f) / (n + 0.01024f)) * n;   // (ncs+eps)/(n+NE*eps)*n
    csn[j] = cs;
    if (j == 0) out[LOSS_OFF] = 0.25f * (lossacc[0] * (1.0f / (float)ZTOT));
}

// ---------------- K3: embed_avg EMA + normalized embedding ----------------
__global__ __launch_bounds__(256) void k_embed(const float* __restrict__ ea_in,
                                               const float* __restrict__ esum,
                                               const float* __restrict__ csn,
                                               float* __restrict__ out) {
    int i = blockIdx.x * 256 + threadIdx.x;   // 0..65535
    float nea = 0.99f * ea_in[i] + 0.01f * esum[i];
    out[EA_OFF + i] = nea;
    out[EMB_OFF + i] = nea / csn[i >> 6];
}

extern "C" void kernel_launch(void* const* d_in, const int* in_sizes, int n_in,
                              void* d_out, int out_size, void* d_ws, size_t ws_size,
                              hipStream_t stream) {
    const float* z   = (const float*)d_in[0];
    const float* emb = (const float*)d_in[1];
    const float* cs  = (const float*)d_in[2];
    const float* ea  = (const float*)d_in[3];
    float* out = (float*)d_out;
    float* ws  = (float*)d_ws;

    hipMemsetAsync(d_ws, 0, 256, stream);   // loss accumulator only
    k_enorm<<<256, 256, 0, stream>>>(emb, ws + WS_ENORM);
    k_fused<<<512, 256, 0, stream>>>(z, emb, ws + WS_ENORM, out, ws + WS_LOSS);
    k_scatter<<<64, 1024, 0, stream>>>(z, out + IDX_OFF, ws + WS_ESUM, ws + WS_COUNTS);
    k_cluster<<<1, 1024, 0, stream>>>(cs, ws + WS_COUNTS, ws + WS_LOSS, out, ws + WS_CSN);
    k_embed<<<256, 256, 0, stream>>>(ea, ws + WS_ESUM, ws + WS_CSN, out);
}

// Round 6
// 183.175 us; speedup vs baseline: 6.8885x; 1.6278x over previous
//
#include <hip/hip_runtime.h>

// Problem constants (fixed shapes from reference)
#define NE    1024
#define CDIM  64
#define BDIM  16
#define HDIM  64
#define WDIM  64
#define NPOS  (BDIM*HDIM*WDIM)          // 65536 positions
#define ZTOT  (BDIM*CDIM*HDIM*WDIM)     // 4194304 elements

// d_out offsets (float elements), concat in reference return order
#define ZQ_OFF   0
#define LOSS_OFF 4194304
#define IDX_OFF  4194305
#define EMB_OFF  4259841
#define CS_OFF   4325377
#define EA_OFF   4326401

// monotone float->uint mapping: a<b  <=>  ordf(a)<ordf(b)
__device__ __forceinline__ unsigned ordf(float x) {
    unsigned b = __float_as_uint(x);
    return (b & 0x80000000u) ? ~b : (b | 0x80000000u);
}

// ---------------- K0: codebook row norms, pre-scaled by -0.5 ----------------
__global__ __launch_bounds__(256) void k_enorm(const float* __restrict__ emb,
                                               float* __restrict__ en2) {
    int wid  = (blockIdx.x * blockDim.x + threadIdx.x) >> 6;   // row 0..1023
    int lane = threadIdx.x & 63;
    if (wid >= NE) return;
    float v = emb[wid * CDIM + lane];
    float s = v * v;
    #pragma unroll
    for (int off = 32; off > 0; off >>= 1) s += __shfl_xor(s, off);
    if (lane == 0) en2[wid] = -0.5f * s;
}

// ---------------- K1: fused argmin GEMM + z_q/idx/loss emit ----------------
// Grid: 512 blocks (2 bh-rows = 128 positions each) x 256 threads (4 waves).
// Register-blocked fp32 GEMM: wave tile 64 pos x 64 codes, lane tile 8x8.
// Argmin key=(ord(m)<<32)|(1023-j) => max-m-then-min-j == first-argmin.
__global__ __launch_bounds__(256) void k_fused(const float* __restrict__ z,
                                               const float* __restrict__ emb,
                                               const float* __restrict__ en2,
                                               float* __restrict__ out,
                                               float* __restrict__ lossacc) {
    __shared__ float zs[64 * 128];            // 32 KB  [c][pl]
    __shared__ float Et[64 * 128];            // 32 KB  [c][jl]
    __shared__ float Nn[128];                 // -0.5||e||^2 for chunk
    __shared__ unsigned long long keyL[128];  // per-position argmin key

    const int t    = threadIdx.x;
    const int lane = t & 63;
    const int wid  = t >> 6;          // wave 0..3
    const int wr   = wid >> 1;        // position half (0..1)
    const int wc   = wid & 1;         // code half (0..1)
    const int lr   = lane >> 3;       // 0..7  position octet selector
    const int lc   = lane & 7;        // 0..7  code octet selector
    const int zb   = wr * 64 + lr * 8;   // lane's first pl
    const int eb   = wc * 64 + lc * 8;   // lane's first jl

    const int blk = blockIdx.x;       // 0..511

    if (t < 128) keyL[t] = 0ull;

    // ---- stage z tile: 2 bh-rows, c-major zs[c][r*64+w] ----
    {
        const int w4 = t & 15;            // float4 index over w
        const int cg = t >> 4;            // 16 c's per pass
        #pragma unroll
        for (int r = 0; r < 2; ++r) {
            const int bh = blk * 2 + r;
            const int b = bh >> 6, h = bh & 63;
            const float* zrow = z + (size_t)b * (CDIM * HDIM * WDIM) + h * WDIM;
            #pragma unroll
            for (int pass = 0; pass < 4; ++pass) {
                const int c = pass * 16 + cg;
                float4 v = *(const float4*)(zrow + c * (HDIM * WDIM) + w4 * 4);
                *(float4*)&zs[c * 128 + r * 64 + w4 * 4] = v;
            }
        }
    }

    const float4* embv = (const float4*)emb;

    float best[8];
    int   bidx[8];
    #pragma unroll
    for (int pi = 0; pi < 8; ++pi) { best[pi] = -3.4e38f; bidx[pi] = 0; }

    for (int ch = 0; ch < 8; ++ch) {
        __syncthreads();   // protect Et/Nn reuse

        // ---- stage E chunk transposed: Et[c][jl] ----
        {
            const int jl = t & 127;
            const int q  = t >> 7;        // 0..1
            #pragma unroll
            for (int qq = 0; qq < 8; ++qq) {
                const int quad = q * 8 + qq;
                float4 e4 = embv[(ch * 128 + jl) * 16 + quad];
                Et[(quad * 4 + 0) * 128 + jl] = e4.x;
                Et[(quad * 4 + 1) * 128 + jl] = e4.y;
                Et[(quad * 4 + 2) * 128 + jl] = e4.z;
                Et[(quad * 4 + 3) * 128 + jl] = e4.w;
            }
        }
        if (t < 128) Nn[t] = en2[ch * 128 + t];
        __syncthreads();

        // ---- GEMM micro-tile: acc[8 pos][8 codes] over 64 channels ----
        float acc[8][8];
        #pragma unroll
        for (int pi = 0; pi < 8; ++pi)
            #pragma unroll
            for (int jj = 0; jj < 8; ++jj) acc[pi][jj] = 0.f;

        #pragma unroll 4
        for (int c = 0; c < 64; ++c) {
            float4 za = *(const float4*)&zs[c * 128 + zb];
            float4 zb4 = *(const float4*)&zs[c * 128 + zb + 4];
            float4 ea = *(const float4*)&Et[c * 128 + eb];
            float4 eb4 = *(const float4*)&Et[c * 128 + eb + 4];
            float zv[8] = {za.x, za.y, za.z, za.w, zb4.x, zb4.y, zb4.z, zb4.w};
            float ev[8] = {ea.x, ea.y, ea.z, ea.w, eb4.x, eb4.y, eb4.z, eb4.w};
            #pragma unroll
            for (int pi = 0; pi < 8; ++pi)
                #pragma unroll
                for (int jj = 0; jj < 8; ++jj)
                    acc[pi][jj] = fmaf(zv[pi], ev[jj], acc[pi][jj]);
        }

        // ---- fold argmin for this chunk ----
        float n2[8];
        {
            float4 na = *(const float4*)&Nn[eb];
            float4 nb = *(const float4*)&Nn[eb + 4];
            n2[0]=na.x; n2[1]=na.y; n2[2]=na.z; n2[3]=na.w;
            n2[4]=nb.x; n2[5]=nb.y; n2[6]=nb.z; n2[7]=nb.w;
        }
        const int jbase = ch * 128 + eb;
        #pragma unroll
        for (int pi = 0; pi < 8; ++pi) {
            #pragma unroll
            for (int jj = 0; jj < 8; ++jj) {
                float m = acc[pi][jj] + n2[jj];
                if (m > best[pi]) { best[pi] = m; bidx[pi] = jbase + jj; }
            }
        }
    }

    // ---- merge across the 8 lc-lanes sharing the same positions ----
    unsigned long long key[8];
    #pragma unroll
    for (int pi = 0; pi < 8; ++pi)
        key[pi] = ((unsigned long long)ordf(best[pi]) << 32) |
                  (unsigned)(1023 - bidx[pi]);
    #pragma unroll
    for (int off = 1; off < 8; off <<= 1) {
        #pragma unroll
        for (int pi = 0; pi < 8; ++pi) {
            unsigned long long o = __shfl_xor(key[pi], off);
            key[pi] = (o > key[pi]) ? o : key[pi];
        }
    }
    #pragma unroll
    for (int pi = 0; pi < 8; ++pi)
        if (lc == pi) atomicMax(&keyL[zb + pi], key[pi]);

    __syncthreads();

    // ---- emit: idx, z_q (straight-through), loss ----
    {
        const int w = t & 63;
        const int g = t >> 6;
        const int r = g & 1;
        const int chalf = g >> 1;
        const int pl = r * 64 + w;
        const int bx = 1023 - (int)(unsigned)(keyL[pl] & 0xFFFFFFFFull);

        if (chalf == 0) out[IDX_OFF + blk * 128 + pl] = (float)bx;

        const int bh = blk * 2 + r;
        const int b = bh >> 6, h = bh & 63;
        float* zqrow = out + ZQ_OFF + (size_t)b * (CDIM * HDIM * WDIM) + h * WDIM + w;

        float lsum = 0.f;
        #pragma unroll
        for (int q = 0; q < 8; ++q) {
            float4 e4 = embv[bx * 16 + chalf * 8 + q];
            #pragma unroll
            for (int k = 0; k < 4; ++k) {
                const int c = chalf * 32 + q * 4 + k;
                float zv = zs[c * 128 + pl];
                float ev = (k == 0) ? e4.x : (k == 1) ? e4.y : (k == 2) ? e4.z : e4.w;
                float df = ev - zv;
                zqrow[c * (HDIM * WDIM)] = zv + df;   // z + (z_q - z)
                lsum = fmaf(df, df, lsum);
            }
        }

        #pragma unroll
        for (int off = 32; off > 0; off >>= 1) lsum += __shfl_xor(lsum, off);
        if (w == 0) atomicAdd(lossacc, lsum);
    }
}

// ---------------- K1b: esum/counts partials, channel x position-slice ----------------
// Grid: nslice*64 blocks; blockIdx = s*64 + c. Each block privatizes its
// slice's 1024-code column in LDS (ds_add_f32) and PLAIN-STORES a partial:
// epart[s][j][c]. c==0 blocks also store count partials. No global atomics.
__global__ __launch_bounds__(1024) void k_scatter(const float* __restrict__ z,
                                                  const float* __restrict__ idxf,
                                                  float* __restrict__ epart,
                                                  float* __restrict__ cntp,
                                                  int nslice) {
    __shared__ float accJ[NE];
    __shared__ float cntJ[NE];

    const int t = threadIdx.x;
    const int c = blockIdx.x & 63;
    const int s = blockIdx.x >> 6;
    accJ[t] = 0.f;
    cntJ[t] = 0.f;
    __syncthreads();

    const bool do_cnt = (c == 0);
    const int per = NPOS / nslice;
    const int p0  = s * per;
    for (int k = 0; k < per; k += 1024) {
        const int p = p0 + k + t;
        const int j = (int)idxf[p];                    // exact for 0..1023
        const int b = p >> 12, hw = p & 4095;
        const float zv = z[(size_t)b * (CDIM * HDIM * WDIM) + c * (HDIM * WDIM) + hw];
        atomicAdd(&accJ[j], zv);                       // ds_add_f32
        if (do_cnt) atomicAdd(&cntJ[j], 1.0f);
    }
    __syncthreads();

    epart[(size_t)s * (NE * CDIM) + t * CDIM + c] = accJ[t];
    if (do_cnt) cntp[s * NE + t] = cntJ[t];
}

// ---------------- K2: cluster-size EMA + n-sum + loss ----------------
__global__ __launch_bounds__(1024) void k_cluster(const float* __restrict__ cs_in,
                                                  const float* __restrict__ cntp,
                                                  const float* __restrict__ lossacc,
                                                  float* __restrict__ out,
                                                  float* __restrict__ csn,
                                                  int nslice) {
    __shared__ float red[NE];
    int j = threadIdx.x;
    float cnt = 0.f;
    for (int s = 0; s < nslice; ++s) cnt += cntp[s * NE + j];   // exact ints
    float ncs = 0.99f * cs_in[j] + 0.01f * cnt;
    out[CS_OFF + j] = ncs;
    red[j] = ncs;
    __syncthreads();
    #pragma unroll
    for (int s = 512; s > 0; s >>= 1) {
        if (j < s) red[j] += red[j + s];
        __syncthreads();
    }
    float n = red[0];
    float cs = ((ncs + 1e-5f) / (n + 0.01024f)) * n;   // (ncs+eps)/(n+NE*eps)*n
    csn[j] = cs;
    if (j == 0) out[LOSS_OFF] = 0.25f * (lossacc[0] * (1.0f / (float)ZTOT));
}

// ---------------- K3: embed_avg EMA + normalized embedding ----------------
__global__ __launch_bounds__(256) void k_embed(const float* __restrict__ ea_in,
                                               const float* __restrict__ epart,
                                               const float* __restrict__ csn,
                                               float* __restrict__ out,
                                               int nslice) {
    int i = blockIdx.x * 256 + threadIdx.x;   // 0..65535
    float es = 0.f;
    for (int s = 0; s < nslice; ++s) es += epart[(size_t)s * (NE * CDIM) + i];
    float nea = 0.99f * ea_in[i] + 0.01f * es;
    out[EA_OFF + i] = nea;
    out[EMB_OFF + i] = nea / csn[i >> 6];
}

extern "C" void kernel_launch(void* const* d_in, const int* in_sizes, int n_in,
                              void* d_out, int out_size, void* d_ws, size_t ws_size,
                              hipStream_t stream) {
    const float* z   = (const float*)d_in[0];
    const float* emb = (const float*)d_in[1];
    const float* cs  = (const float*)d_in[2];
    const float* ea  = (const float*)d_in[3];
    float* out = (float*)d_out;
    float* ws  = (float*)d_ws;

    // pick slice count that fits the workspace (deterministic for fixed ws_size)
    int ns = 8;
    while (ns > 1) {
        size_t need = (size_t)(64 + ns * NE + (size_t)ns * NE * CDIM + 2 * NE) * 4;
        if (need <= ws_size) break;
        ns >>= 1;
    }
    float* ws_loss  = ws;                            // 1 (zeroed)
    float* ws_cntp  = ws + 64;                       // ns*1024
    float* ws_epart = ws_cntp + ns * NE;             // ns*65536
    float* ws_enorm = ws_epart + (size_t)ns * NE * CDIM;  // 1024
    float* ws_csn   = ws_enorm + NE;                 // 1024

    hipMemsetAsync(ws_loss, 0, 256, stream);   // loss accumulator only
    k_enorm<<<256, 256, 0, stream>>>(emb, ws_enorm);
    k_fused<<<512, 256, 0, stream>>>(z, emb, ws_enorm, out, ws_loss);
    k_scatter<<<ns * 64, 1024, 0, stream>>>(z, out + IDX_OFF, ws_epart, ws_cntp, ns);
    k_cluster<<<1, 1024, 0, stream>>>(cs, ws_cntp, ws_loss, out, ws_csn, ns);
    k_embed<<<256, 256, 0, stream>>>(ea, ws_epart, ws_csn, out, ns);
}